// Round 8
// baseline (296.537 us; speedup 1.0000x reference)
//
#include <hip/hip_runtime.h>
#include <stdint.h>

// ============================================================================
// DilatedConv feedback: y_t = y_{t-1} @ A + c_t,  c_t = x[:,:,t+256] @ W1T
// Chunked scan (L=16, NCH=496):
//   cgemm_m : c_t -> cbuf[t][b][o] bf16. v4: x staged once into [t][c] LDS
//             with FULL-bank swizzle swz5(t)=((t&3)<<3)^((t>>2)&31) on the
//             dword index (b32 writes AND b32 frag reads -> 2-way=free both
//             sides; fixes r7's 15.2M bank conflicts). Fragments stored
//             directly to cbuf as scattered b16 (r6-proven, no amp).
//   phase1  : per-chunk local scan (zero init, hi/lo bf16 state) ->
//             ylocal_t overwrites cbuf slice IN PLACE + E_j to Ebuf   [MFMA]
//   binit   : initbuf[k+1] = E_k + E_{k-1} @ A^16 (PARALLEL truncation)
//   corr    : y_t = ylocal_t + Z_{i+1}, Z_{i+1} = Z_i @ A (bf16 chain)
//   yout    : transpose cbuf [t][b][o] -> out [b][o][t+1] via LDS tiles
// Runtime ws_size guard: falls back to round-1 VALU path if ws too small.
// ============================================================================

constexpr int BATCH  = 16;
constexpr int CH     = 256;
constexpr int NEL    = 8192;
constexpr int NDIL   = 256;
constexpr int TSTEPS = NEL - (NDIL + 1);          // 7935
constexpr int LCH    = 16;
constexpr int NCH    = (TSTEPS + LCH - 1) / LCH;   // 496
constexpr int TPB    = 256;
constexpr int YPAD   = 260;                        // fallback scan state pad
constexpr int A2PAD  = 264;
constexpr int TTILES = (TSTEPS + 127) / 128;       // 62
constexpr int YROW   = 264;                        // bf16 state row (pad)

// workspace offsets (bytes)
constexpr size_t OFF_AF    = 0;
constexpr size_t OFF_P1    = OFF_AF    + 256 * 1024;
constexpr size_t OFF_P2    = OFF_P1    + 256 * 1024;
constexpr size_t OFF_AB16  = OFF_P2    + 256 * 1024;
constexpr size_t OFF_W1B   = OFF_AB16  + 128 * 1024;
constexpr size_t OFF_E     = OFF_W1B   + 128 * 1024;
constexpr size_t OFF_INIT  = OFF_E     + (size_t)NCH * BATCH * CH * 4;
constexpr size_t OFF_AFRAG = OFF_INIT  + (size_t)(NCH + 1) * BATCH * CH * 4;
constexpr size_t OFF_W1FR  = OFF_AFRAG + 128 * 1024;
constexpr size_t OFF_CBUF  = OFF_W1FR  + 128 * 1024;
constexpr size_t CBUF_BYTES = (size_t)(NCH * LCH) * BATCH * CH * 2;  // bf16
constexpr size_t WS_NEED   = OFF_CBUF + CBUF_BYTES;                  // ~90MB

typedef __attribute__((ext_vector_type(8))) short bf16x8;
typedef __attribute__((ext_vector_type(4))) float f32x4;

__device__ __forceinline__ float bfu(uint32_t hibits) { return __uint_as_float(hibits); }
__device__ __forceinline__ float bf2f(uint16_t b) { return __uint_as_float(((uint32_t)b) << 16); }
__device__ __forceinline__ uint16_t f2bf(float f) {          // RNE float->bf16
  uint32_t u = __float_as_uint(f);
  uint32_t r = u + 0x7fffu + ((u >> 16) & 1u);
  return (uint16_t)(r >> 16);
}

// ---------------------------------------------------------------- prep weights
// Afrag/W1frag = B-fragment-ordered (validated layout):
// frag(kb,nt): lane l, elem i  <=  M[kb*32 + (l>>4)*8 + i][nt*16 + (l&15)]
__global__ void k_prep(const float* __restrict__ w, float* __restrict__ Af,
                       uint16_t* __restrict__ Ab, uint16_t* __restrict__ W1b,
                       uint16_t* __restrict__ Afrag, uint16_t* __restrict__ W1f) {
  int o = blockIdx.x, c = threadIdx.x;
  const float2 wv = *(const float2*)&w[(size_t)(o * CH + c) * 2];
  Af[c * CH + o]  = wv.x;
  Ab[c * CH + o]  = f2bf(wv.x);
  W1b[c * CH + o] = f2bf(wv.y);
  if (Afrag) {
    int kb = c >> 5, g = (c >> 3) & 3, ii = c & 7;
    int nt = o >> 4, mm = o & 15;
    size_t idx = (((size_t)(kb * 16 + nt) * 64) + (g * 16 + mm)) * 8 + ii;
    Afrag[idx] = f2bf(wv.x);
    W1f[idx]   = f2bf(wv.y);
  }
}

__global__ void k_init0(const float* __restrict__ x, float* __restrict__ initbuf) {
  int b = blockIdx.x, c = threadIdx.x;
  initbuf[b * CH + c] = x[(size_t)(b * CH + c) * NEL];
}

__global__ __launch_bounds__(TPB) void k_sqmm(const float* __restrict__ in,
                                              float* __restrict__ outm) {
  __shared__ __align__(16) float row[CH];
  int r = blockIdx.x, o = threadIdx.x;
  row[o] = in[r * CH + o];
  __syncthreads();
  float acc = 0.f;
#pragma unroll 8
  for (int k = 0; k < CH; ++k) acc += row[k] * in[k * CH + o];
  outm[r * CH + o] = acc;
}

__global__ void k_edges(const float* __restrict__ x, float* __restrict__ out) {
  size_t base = (size_t)blockIdx.x * NEL;
  int t = threadIdx.x;
  out[base + (NEL - 256) + t] = x[base + (NEL - 256) + t];
  if (t == 0) out[base] = x[base];
}

// ------------------- MFMA cGEMM v4: cbuf[t][b*256+o] = bf16( x_{t+256} @ W1T )
// Block 512 thr (8 waves), tile 128t x 256o, one b. [t][c] bf16 LDS with
// dword-index swizzle swz5(t) = ((t&3)<<3) ^ ((t>>2)&31):
//   write: bank = c/2 ^ (k<<3) ^ tau -> tau sweeps 32 banks -> 2-way (free)
//   read : 4 x ds_read_b32 per frag  -> <=2 lanes/bank (free)
// Fragments store directly to cbuf (scattered b16, r6-proven exact WRITE).
__global__ __launch_bounds__(512, 2) void k_cgemm_m(const float* __restrict__ x,
                                                    const uint16_t* __restrict__ W1f,
                                                    uint16_t* __restrict__ cb) {
  __shared__ __align__(16) uint32_t xsw[128 * 128];  // 64KB [t][c] bf16 pairs
  int tid = threadIdx.x, bid = blockIdx.x;
  int b = bid / TTILES, tt = bid % TTILES;
  int t0 = tt * 128;
  const float* xb = x + (size_t)b * CH * NEL + (t0 + NDIL);

  // ---- stage: 8 iters; thread: c-pair p = tid>>5, t-quad tau = tid&31
  int p = tid >> 5, tau = tid & 31;
#pragma unroll
  for (int it = 0; it < 8; ++it) {
    int c0 = it * 32 + p * 2;
    float4 va = *(const float4*)&xb[(size_t)c0 * NEL + tau * 4];
    float4 vb = *(const float4*)&xb[(size_t)(c0 + 1) * NEL + tau * 4];
    float fa[4] = {va.x, va.y, va.z, va.w};
    float fb[4] = {vb.x, vb.y, vb.z, vb.w};
#pragma unroll
    for (int k = 0; k < 4; ++k) {
      int t = tau * 4 + k;
      uint32_t pk = (uint32_t)f2bf(fa[k]) | ((uint32_t)f2bf(fb[k]) << 16);
      int dw = t * 128 + c0 / 2;
      int swz = ((t & 3) << 3) ^ ((t >> 2) & 31);
      xsw[dw ^ swz] = pk;
    }
  }
  __syncthreads();

  // ---- compute: wave w owns t-rows w*16..w*16+15, all 16 n-tiles
  int w = tid >> 6, l = tid & 63, lm = l & 15, g = l >> 4;
  int t = w * 16 + lm;
  int swz = ((t & 3) << 3) ^ ((t >> 2) & 31);
  int dwrow = t * 128;
  f32x4 acc[16];
#pragma unroll
  for (int nt = 0; nt < 16; ++nt) acc[nt] = (f32x4)0.f;
#pragma unroll
  for (int kb = 0; kb < 8; ++kb) {
    bf16x8 av;
    uint32_t* avp = (uint32_t*)&av;
    int dwb = dwrow + kb * 16 + g * 4;
#pragma unroll
    for (int s = 0; s < 4; ++s) avp[s] = xsw[(dwb + s) ^ swz];
#pragma unroll
    for (int nt = 0; nt < 16; ++nt) {
      bf16x8 bv = *(const bf16x8*)&W1f[(((size_t)(kb * 16 + nt) * 64) + l) * 8];
      acc[nt] = __builtin_amdgcn_mfma_f32_16x16x32_bf16(av, bv, acc[nt], 0, 0, 0);
    }
  }
  // ---- direct scattered b16 stores
#pragma unroll
  for (int nt = 0; nt < 16; ++nt)
#pragma unroll
    for (int r = 0; r < 4; ++r) {
      int t2 = t0 + w * 16 + g * 4 + r;
      if (t2 < TSTEPS)
        cb[(size_t)t2 * (BATCH * CH) + b * CH + nt * 16 + lm] = f2bf(acc[nt][r]);
    }
}

// --------------------------------------------------- phase1 MFMA chunk scan
// Read Y from buf R, MFMA (c-init from prefetched regs), write buf W + ylocal
// to cbuf IN PLACE, ONE raw barrier (LDS drain only; global ops fly across).
__device__ __forceinline__ void scan_step(
    int t, bool pref, const uint16_t* YhR, const uint16_t* YlR,
    uint16_t* YhW, uint16_t* YlW, uint16_t* __restrict__ cb,
    const bf16x8 af[8][4], ushort* ccC, ushort* ccN,
    f32x4 acc[4], int w, int lm, int g) {
  if (pref) {  // issue c_{t+1} loads early (consumed next step)
    size_t cbase = (size_t)(t + 1) * (BATCH * CH);
#pragma unroll
    for (int ntl = 0; ntl < 4; ++ntl)
#pragma unroll
      for (int r = 0; r < 4; ++r)
        ccN[ntl * 4 + r] = cb[cbase + (g * 4 + r) * CH + (w * 4 + ntl) * 16 + lm];
  }
  bf16x8 yv[8];
  // lo pass (acc init from prefetched c regs)
#pragma unroll
  for (int kb = 0; kb < 8; ++kb)
    yv[kb] = *(const bf16x8*)&YlR[lm * YROW + kb * 32 + g * 8];
#pragma unroll
  for (int ntl = 0; ntl < 4; ++ntl) {
#pragma unroll
    for (int r = 0; r < 4; ++r)
      acc[ntl][r] = bfu(((uint32_t)ccC[ntl * 4 + r]) << 16);
#pragma unroll
    for (int kb = 0; kb < 8; ++kb)
      acc[ntl] = __builtin_amdgcn_mfma_f32_16x16x32_bf16(yv[kb], af[kb][ntl], acc[ntl], 0, 0, 0);
  }
  // hi pass (reuse yv regs)
#pragma unroll
  for (int kb = 0; kb < 8; ++kb)
    yv[kb] = *(const bf16x8*)&YhR[lm * YROW + kb * 32 + g * 8];
#pragma unroll
  for (int ntl = 0; ntl < 4; ++ntl) {
#pragma unroll
    for (int kb = 0; kb < 8; ++kb)
      acc[ntl] = __builtin_amdgcn_mfma_f32_16x16x32_bf16(yv[kb], af[kb][ntl], acc[ntl], 0, 0, 0);
  }
  size_t ybase = (size_t)t * (BATCH * CH);
#pragma unroll
  for (int ntl = 0; ntl < 4; ++ntl)
#pragma unroll
    for (int r = 0; r < 4; ++r) {
      float v = acc[ntl][r];
      int b = g * 4 + r, o = (w * 4 + ntl) * 16 + lm;
      uint16_t hb = f2bf(v);
      cb[ybase + b * CH + o] = hb;  // ylocal in place (vmcnt; flies over barrier)
      YhW[b * YROW + o] = hb;
      YlW[b * YROW + o] = f2bf(v - bf2f(hb));
    }
  asm volatile("s_waitcnt lgkmcnt(0)" ::: "memory");
  __builtin_amdgcn_sched_barrier(0);
  __builtin_amdgcn_s_barrier();
  __builtin_amdgcn_sched_barrier(0);
}

__global__ __launch_bounds__(TPB, 1) void k_scanm(
    const uint16_t* __restrict__ Afrag, uint16_t* __restrict__ cb,
    float* __restrict__ Ebuf) {
  __shared__ __align__(16) uint16_t Yh[2][16 * YROW];
  __shared__ __align__(16) uint16_t Yl[2][16 * YROW];
  int tid = threadIdx.x;
  int j = blockIdx.x;
  int w = tid >> 6, l = tid & 63;
  int lm = l & 15, g = l >> 4;

  bf16x8 af[8][4];
#pragma unroll
  for (int kb = 0; kb < 8; ++kb)
#pragma unroll
    for (int ntl = 0; ntl < 4; ++ntl) {
      int nt = w * 4 + ntl;
      af[kb][ntl] = *(const bf16x8*)&Afrag[(((size_t)(kb * 16 + nt) * 64) + l) * 8];
    }

  for (int q = tid; q < 16 * YROW; q += TPB) { Yh[0][q] = 0; Yl[0][q] = 0; }

  int t0 = j * LCH;
  int len = min(LCH, TSTEPS - t0);
  ushort c0[16], c1[16];
  {  // prologue: load c_{t0} in fragment order
    size_t cbase = (size_t)t0 * (BATCH * CH);
#pragma unroll
    for (int ntl = 0; ntl < 4; ++ntl)
#pragma unroll
      for (int r = 0; r < 4; ++r)
        c0[ntl * 4 + r] = cb[cbase + (g * 4 + r) * CH + (w * 4 + ntl) * 16 + lm];
  }
  __syncthreads();

  f32x4 acc[4];
#pragma unroll 1
  for (int ii = 0; ii < LCH; ii += 2) {
    if (ii >= len) break;
    scan_step(t0 + ii, ii + 1 < len, Yh[0], Yl[0], Yh[1], Yl[1], cb,
              af, c0, c1, acc, w, lm, g);
    if (ii + 1 >= len) break;
    scan_step(t0 + ii + 1, ii + 2 < len, Yh[1], Yl[1], Yh[0], Yl[0], cb,
              af, c1, c0, acc, w, lm, g);
  }
  // E_j = final local state (fp32, from last step's acc)
#pragma unroll
  for (int ntl = 0; ntl < 4; ++ntl) {
    int nt = w * 4 + ntl;
#pragma unroll
    for (int r = 0; r < 4; ++r) {
      int b = g * 4 + r, o = nt * 16 + lm;
      Ebuf[(size_t)j * (BATCH * CH) + b * CH + o] = acc[ntl][r];
    }
  }
}

// ------------------- binit: initbuf[k+1] = E_k + P_k @ A^L, P_k = E_{k-1}|x0
__global__ __launch_bounds__(TPB) void k_binit(const float* __restrict__ AL,
                                               const float* __restrict__ Ebuf,
                                               float* __restrict__ initbuf) {
  int k = blockIdx.x, o = threadIdx.x;
  const float* __restrict__ P =
      (k == 0) ? initbuf : (Ebuf + (size_t)(k - 1) * (BATCH * CH));
  const float* __restrict__ Ek = Ebuf + (size_t)k * (BATCH * CH);
  float acc[BATCH];
#pragma unroll
  for (int b = 0; b < BATCH; ++b) acc[b] = Ek[b * CH + o];
#pragma unroll 4
  for (int c = 0; c < CH; ++c) {
    float a = AL[c * CH + o];
#pragma unroll
    for (int b = 0; b < BATCH; ++b) acc[b] += P[b * CH + c] * a;
  }
  float* __restrict__ D = initbuf + (size_t)(k + 1) * (BATCH * CH);
#pragma unroll
  for (int b = 0; b < BATCH; ++b) D[b * CH + o] = acc[b];
}

// ------------------- corr: y_t = ylocal_t + Z_{i+1}, Z_{i+1} = Z_i @ A
// Single-bf16 correction chain (decays rho~0.707/step). One barrier/step.
__device__ __forceinline__ void corr_step(
    int t, bool pref, const uint16_t* Zr, uint16_t* Zw,
    uint16_t* __restrict__ cb, const bf16x8 af[8][4],
    ushort* ccC, ushort* ccN, int w, int lm, int g) {
  if (pref) {  // prefetch ylocal row t+1
    size_t cbase = (size_t)(t + 1) * (BATCH * CH);
#pragma unroll
    for (int ntl = 0; ntl < 4; ++ntl)
#pragma unroll
      for (int r = 0; r < 4; ++r)
        ccN[ntl * 4 + r] = cb[cbase + (g * 4 + r) * CH + (w * 4 + ntl) * 16 + lm];
  }
  bf16x8 zv[8];
#pragma unroll
  for (int kb = 0; kb < 8; ++kb)
    zv[kb] = *(const bf16x8*)&Zr[lm * YROW + kb * 32 + g * 8];
  f32x4 acc[4];
#pragma unroll
  for (int ntl = 0; ntl < 4; ++ntl) {
    acc[ntl] = (f32x4)0.f;
#pragma unroll
    for (int kb = 0; kb < 8; ++kb)
      acc[ntl] = __builtin_amdgcn_mfma_f32_16x16x32_bf16(zv[kb], af[kb][ntl], acc[ntl], 0, 0, 0);
  }
  size_t ybase = (size_t)t * (BATCH * CH);
#pragma unroll
  for (int ntl = 0; ntl < 4; ++ntl)
#pragma unroll
    for (int r = 0; r < 4; ++r) {
      int b = g * 4 + r, o = (w * 4 + ntl) * 16 + lm;
      float z = acc[ntl][r];
      float y = bfu(((uint32_t)ccC[ntl * 4 + r]) << 16) + z;
      cb[ybase + b * CH + o] = f2bf(y);   // final y (global store, flies)
      Zw[b * YROW + o] = f2bf(z);
    }
  asm volatile("s_waitcnt lgkmcnt(0)" ::: "memory");
  __builtin_amdgcn_sched_barrier(0);
  __builtin_amdgcn_s_barrier();
  __builtin_amdgcn_sched_barrier(0);
}

__global__ __launch_bounds__(TPB, 1) void k_corr(
    const uint16_t* __restrict__ Afrag, uint16_t* __restrict__ cb,
    const float* __restrict__ initbuf) {
  __shared__ __align__(16) uint16_t Z[2][16 * YROW];
  int tid = threadIdx.x;
  int j = blockIdx.x;
  int w = tid >> 6, l = tid & 63;
  int lm = l & 15, g = l >> 4;

  bf16x8 af[8][4];
#pragma unroll
  for (int kb = 0; kb < 8; ++kb)
#pragma unroll
    for (int ntl = 0; ntl < 4; ++ntl) {
      int nt = w * 4 + ntl;
      af[kb][ntl] = *(const bf16x8*)&Afrag[(((size_t)(kb * 16 + nt) * 64) + l) * 8];
    }

  {  // Z_0 = bf16(B_{j-1})
    const float* I = initbuf + (size_t)j * (BATCH * CH);
    int b = tid >> 4, o0 = (tid & 15) * 16;
#pragma unroll
    for (int q = 0; q < 16; ++q)
      Z[0][b * YROW + o0 + q] = f2bf(I[b * CH + o0 + q]);
  }

  int t0 = j * LCH;
  int len = min(LCH, TSTEPS - t0);
  ushort c0[16], c1[16];
  {  // prologue: prefetch ylocal row t0
    size_t cbase = (size_t)t0 * (BATCH * CH);
#pragma unroll
    for (int ntl = 0; ntl < 4; ++ntl)
#pragma unroll
      for (int r = 0; r < 4; ++r)
        c0[ntl * 4 + r] = cb[cbase + (g * 4 + r) * CH + (w * 4 + ntl) * 16 + lm];
  }
  __syncthreads();

#pragma unroll 1
  for (int ii = 0; ii < LCH; ii += 2) {
    if (ii >= len) break;
    corr_step(t0 + ii, ii + 1 < len, Z[0], Z[1], cb, af, c0, c1, w, lm, g);
    if (ii + 1 >= len) break;
    corr_step(t0 + ii + 1, ii + 2 < len, Z[1], Z[0], cb, af, c1, c0, w, lm, g);
  }
}

// ------------------- yout: transpose cbuf [t][b][o] bf16 -> out [b][o][t+1] f32
__global__ __launch_bounds__(TPB) void k_yout(const uint16_t* __restrict__ cb,
                                              float* __restrict__ out) {
  __shared__ __align__(16) float tile[64][65];
  int bid = blockIdx.x;
  int ot = bid & 3, b = (bid >> 2) & 15, tt = bid >> 6;  // tt 0..123
  int t0 = tt * 64, o0 = ot * 64;
  int tid = threadIdx.x;
  {  // load 64t x 64o bf16 (coalesced along o), convert to f32 in LDS
    int tl = tid >> 2, oq = (tid & 3) * 16;
    const uint16_t* src = &cb[(size_t)(t0 + tl) * (BATCH * CH) + b * CH + o0 + oq];
    uint4 u0 = *(const uint4*)src;
    uint4 u1 = *(const uint4*)(src + 8);
    uint32_t u[8] = {u0.x, u0.y, u0.z, u0.w, u1.x, u1.y, u1.z, u1.w};
#pragma unroll
    for (int k = 0; k < 8; ++k) {
      tile[tl][oq + 2 * k]     = bfu(u[k] << 16);
      tile[tl][oq + 2 * k + 1] = bfu(u[k] & 0xffff0000u);
    }
  }
  __syncthreads();
  {  // store 64 contiguous t per o-row (full-line writes)
    int ol = tid >> 2, tq = (tid & 3) * 16;
    float* dst = &out[(size_t)(b * CH + o0 + ol) * NEL + 1 + t0 + tq];
    if (t0 + tq + 15 < TSTEPS) {
#pragma unroll
      for (int k4 = 0; k4 < 4; ++k4) {
        float4 f;
        f.x = tile[tq + 4 * k4 + 0][ol];
        f.y = tile[tq + 4 * k4 + 1][ol];
        f.z = tile[tq + 4 * k4 + 2][ol];
        f.w = tile[tq + 4 * k4 + 3][ol];
        *(float4*)&dst[4 * k4] = f;
      }
    } else {
#pragma unroll
      for (int k = 0; k < 16; ++k)
        if (t0 + tq + k < TSTEPS) dst[k] = tile[tq + k][ol];
    }
  }
}

// ======================= fallback path (round-1, proven) =====================
__global__ __launch_bounds__(TPB) void k_cgemm_v(const float* __restrict__ x,
                                                 const uint16_t* __restrict__ W1b,
                                                 float* __restrict__ out) {
  __shared__ __align__(16) uint16_t w1[CH * 128];
  __shared__ __align__(16) float xs[32][128];
  int tid = threadIdx.x;
  int bid = blockIdx.x;
  int b = bid / (TTILES * 2);
  int rem = bid % (TTILES * 2);
  int ttile = rem >> 1, otile = rem & 1;
  int t0 = ttile * 128, o0 = otile * 128;
  int tx = tid & 15, ty = tid >> 4;
  int o8 = o0 + tx * 8;
  int tb = t0 + ty * 8;
  {
    uint4* dst = (uint4*)w1;
    for (int q = tid; q < CH * 128 / 8; q += TPB) {
      int row = q >> 4, seg = q & 15;
      dst[q] = *(const uint4*)&W1b[row * CH + o0 + seg * 8];
    }
  }
  float acc[8][8];
#pragma unroll
  for (int i = 0; i < 8; ++i)
#pragma unroll
    for (int j = 0; j < 8; ++j) acc[i][j] = 0.f;
  for (int c0 = 0; c0 < CH; c0 += 32) {
    __syncthreads();
#pragma unroll
    for (int kk = 0; kk < 4; ++kk) {
      int q = tid + kk * TPB;
      int cc = q >> 5, tf = (q & 31) * 4;
      *(float4*)&xs[cc][tf] =
          *(const float4*)&x[(size_t)(b * CH + c0 + cc) * NEL + t0 + NDIL + tf];
    }
    __syncthreads();
#pragma unroll 4
    for (int cc = 0; cc < 32; ++cc) {
      float4 xa = *(const float4*)&xs[cc][ty * 8];
      float4 xb = *(const float4*)&xs[cc][ty * 8 + 4];
      float xv[8] = {xa.x, xa.y, xa.z, xa.w, xb.x, xb.y, xb.z, xb.w};
      uint4 wv = *(const uint4*)&w1[(c0 + cc) * 128 + tx * 8];
      float wf[8] = {bfu(wv.x << 16), bfu(wv.x & 0xffff0000u),
                     bfu(wv.y << 16), bfu(wv.y & 0xffff0000u),
                     bfu(wv.z << 16), bfu(wv.z & 0xffff0000u),
                     bfu(wv.w << 16), bfu(wv.w & 0xffff0000u)};
#pragma unroll
      for (int i = 0; i < 8; ++i)
#pragma unroll
        for (int j = 0; j < 8; ++j) acc[i][j] += xv[i] * wf[j];
    }
  }
#pragma unroll
  for (int j = 0; j < 8; ++j) {
    size_t base = (size_t)(b * CH + o8 + j) * NEL + tb + 1;
#pragma unroll
    for (int i = 0; i < 8; ++i)
      if (tb + i < TSTEPS) out[base + i] = acc[i][j];
  }
}

template <bool PH3>
__global__ __launch_bounds__(TPB) void k_scan(const uint16_t* __restrict__ Ab,
                                              const float* __restrict__ initbuf,
                                              float* __restrict__ Ebuf,
                                              float* __restrict__ out) {
  __shared__ __align__(16) uint16_t Al[CH * CH];
  __shared__ __align__(16) float yl[BATCH * YPAD];
  int tid = threadIdx.x;
  int j = blockIdx.x;
  {
    const uint4* src = (const uint4*)Ab;
    uint4* dst = (uint4*)Al;
    for (int q = tid; q < CH * CH / 8; q += TPB) dst[q] = src[q];
  }
  if constexpr (PH3) {
    for (int q = tid; q < BATCH * CH / 4; q += TPB) {
      int b = q >> 6, c4 = (q & 63) * 4;
      *(float4*)&yl[b * YPAD + c4] =
          *(const float4*)&initbuf[(size_t)j * BATCH * CH + b * CH + c4];
    }
  } else {
    for (int q = tid; q < BATCH * YPAD; q += TPB) yl[q] = 0.f;
  }
  __syncthreads();
  int o4 = (tid & 63) * 4;
  int b4 = (tid >> 6) * 4;
  int len = min(LCH, TSTEPS - j * LCH);
  float acc[4][4];
  for (int i = 0; i < len; ++i) {
    int t = j * LCH + i;
    float cv[4][4];
#pragma unroll
    for (int bb = 0; bb < 4; ++bb)
#pragma unroll
      for (int oo = 0; oo < 4; ++oo)
        cv[bb][oo] = out[(size_t)((b4 + bb) * CH + o4 + oo) * NEL + t + 1];
#pragma unroll
    for (int bb = 0; bb < 4; ++bb)
#pragma unroll
      for (int oo = 0; oo < 4; ++oo) acc[bb][oo] = 0.f;
#pragma unroll 2
    for (int c = 0; c < CH; c += 4) {
      float4 v0 = *(const float4*)&yl[(b4 + 0) * YPAD + c];
      float4 v1 = *(const float4*)&yl[(b4 + 1) * YPAD + c];
      float4 v2 = *(const float4*)&yl[(b4 + 2) * YPAD + c];
      float4 v3 = *(const float4*)&yl[(b4 + 3) * YPAD + c];
      float y0[4] = {v0.x, v0.y, v0.z, v0.w};
      float y1[4] = {v1.x, v1.y, v1.z, v1.w};
      float y2[4] = {v2.x, v2.y, v2.z, v2.w};
      float y3[4] = {v3.x, v3.y, v3.z, v3.w};
#pragma unroll
      for (int k = 0; k < 4; ++k) {
        uint2 au = *(const uint2*)&Al[(c + k) * CH + o4];
        float a[4] = {bfu(au.x << 16), bfu(au.x & 0xffff0000u),
                      bfu(au.y << 16), bfu(au.y & 0xffff0000u)};
#pragma unroll
        for (int oo = 0; oo < 4; ++oo) {
          acc[0][oo] += y0[k] * a[oo];
          acc[1][oo] += y1[k] * a[oo];
          acc[2][oo] += y2[k] * a[oo];
          acc[3][oo] += y3[k] * a[oo];
        }
      }
    }
#pragma unroll
    for (int bb = 0; bb < 4; ++bb)
#pragma unroll
      for (int oo = 0; oo < 4; ++oo) acc[bb][oo] += cv[bb][oo];
    __syncthreads();
#pragma unroll
    for (int bb = 0; bb < 4; ++bb)
      *(float4*)&yl[(b4 + bb) * YPAD + o4] =
          make_float4(acc[bb][0], acc[bb][1], acc[bb][2], acc[bb][3]);
    if constexpr (PH3) {
#pragma unroll
      for (int bb = 0; bb < 4; ++bb)
#pragma unroll
        for (int oo = 0; oo < 4; ++oo)
          out[(size_t)((b4 + bb) * CH + o4 + oo) * NEL + t + 1] = acc[bb][oo];
    }
    __syncthreads();
  }
  if constexpr (!PH3) {
#pragma unroll
    for (int bb = 0; bb < 4; ++bb)
#pragma unroll
      for (int oo = 0; oo < 4; ++oo)
        Ebuf[(size_t)j * BATCH * CH + (b4 + bb) * CH + o4 + oo] = acc[bb][oo];
  }
}

__global__ __launch_bounds__(TPB) void k_phase2(const float* __restrict__ ALf,
                                                const float* __restrict__ Ebuf,
                                                float* __restrict__ initbuf) {
  __shared__ __align__(16) uint16_t At[CH * A2PAD];
  __shared__ __align__(16) float st[CH];
  int b = blockIdx.x, tid = threadIdx.x;
  for (int q = tid; q < CH * CH; q += TPB) {
    int c = q >> 8, o = q & 255;
    At[o * A2PAD + c] = f2bf(ALf[q]);
  }
  st[tid] = initbuf[b * CH + tid];
  __syncthreads();
  for (int jj = 1; jj < NCH; ++jj) {
    float acc = Ebuf[(size_t)(jj - 1) * BATCH * CH + b * CH + tid];
#pragma unroll 4
    for (int c = 0; c < CH; c += 8) {
      uint4 au = *(const uint4*)&At[tid * A2PAD + c];
      float4 s0 = *(const float4*)&st[c];
      float4 s1 = *(const float4*)&st[c + 4];
      acc += bfu(au.x << 16) * s0.x + bfu(au.x & 0xffff0000u) * s0.y +
             bfu(au.y << 16) * s0.z + bfu(au.y & 0xffff0000u) * s0.w +
             bfu(au.z << 16) * s1.x + bfu(au.z & 0xffff0000u) * s1.y +
             bfu(au.w << 16) * s1.z + bfu(au.w & 0xffff0000u) * s1.w;
    }
    __syncthreads();
    st[tid] = acc;
    initbuf[(size_t)jj * BATCH * CH + b * CH + tid] = acc;
    __syncthreads();
  }
}

// ============================================================================
extern "C" void kernel_launch(void* const* d_in, const int* in_sizes, int n_in,
                              void* d_out, int out_size, void* d_ws, size_t ws_size,
                              hipStream_t stream) {
  const float* x = (const float*)d_in[0];
  const float* w = (const float*)d_in[1];
  float* out = (float*)d_out;
  char* ws = (char*)d_ws;

  float*    Af    = (float*)(ws + OFF_AF);
  float*    P1    = (float*)(ws + OFF_P1);
  float*    P2    = (float*)(ws + OFF_P2);
  uint16_t* Ab    = (uint16_t*)(ws + OFF_AB16);
  uint16_t* W1b   = (uint16_t*)(ws + OFF_W1B);
  float*    Ebuf  = (float*)(ws + OFF_E);
  float*    inb   = (float*)(ws + OFF_INIT);
  uint16_t* Afrag = (uint16_t*)(ws + OFF_AFRAG);
  uint16_t* W1f   = (uint16_t*)(ws + OFF_W1FR);
  uint16_t* cbuf  = (uint16_t*)(ws + OFF_CBUF);

  const bool fast = ws_size >= WS_NEED;

  k_prep<<<CH, CH, 0, stream>>>(w, Af, Ab, W1b, fast ? Afrag : nullptr, W1f);
  k_init0<<<BATCH, CH, 0, stream>>>(x, inb);
  k_sqmm<<<CH, TPB, 0, stream>>>(Af, P1);   // A^2
  k_sqmm<<<CH, TPB, 0, stream>>>(P1, P2);   // A^4
  k_sqmm<<<CH, TPB, 0, stream>>>(P2, P1);   // A^8
  k_sqmm<<<CH, TPB, 0, stream>>>(P1, P2);   // A^16 (= A^LCH)
  k_edges<<<BATCH * CH, 256, 0, stream>>>(x, out);
  if (fast) {
    k_cgemm_m<<<BATCH * TTILES, 512, 0, stream>>>(x, W1f, cbuf);
    k_scanm<<<NCH, TPB, 0, stream>>>(Afrag, cbuf, Ebuf);
    k_binit<<<NCH - 1, TPB, 0, stream>>>(P2, Ebuf, inb);
    k_corr<<<NCH, TPB, 0, stream>>>(Afrag, cbuf, inb);
    k_yout<<<124 * 64, TPB, 0, stream>>>(cbuf, out);
  } else {
    k_cgemm_v<<<BATCH * TTILES * 2, TPB, 0, stream>>>(x, W1b, out);
    k_scan<false><<<NCH - 1, TPB, 0, stream>>>(Ab, nullptr, Ebuf, out);
    k_phase2<<<BATCH, TPB, 0, stream>>>(P2, Ebuf, inb);
    k_scan<true><<<NCH, TPB, 0, stream>>>(Ab, inb, nullptr, out);
  }
}

// Round 9
// 278.248 us; speedup vs baseline: 1.0657x; 1.0657x over previous
//
#include <hip/hip_runtime.h>
#include <stdint.h>

// ============================================================================
// DilatedConv feedback: y_t = y_{t-1} @ A + c_t,  c_t = x[:,:,t+256] @ W1T
// Chunked scan (L=16, NCH=496):
//   cgemm_m : c_t -> cbuf[t][b][o] bf16. v5: W1 fragments REGISTER-resident
//             (r8 lesson: per-MFMA global bv loads = 1MB/block L1-thrash was
//             the latency bottleneck, not LDS conflicts). x staged to LDS in
//             A-fragment-major order (ds_write_b128/ds_read_b128, standard
//             conflict-free pattern). 2 blocks/CU.
//   phase1  : per-chunk local scan (zero init, hi/lo bf16 state) ->
//             ylocal_t overwrites cbuf slice IN PLACE + E_j to Ebuf   [MFMA]
//   binit   : initbuf[k+1] = E_k + E_{k-1} @ A^16 (PARALLEL truncation)
//   corr    : y_t = ylocal_t + Z_{i+1}, Z_{i+1} = Z_i @ A (bf16 chain)
//   yout    : transpose cbuf [t][b][o] -> out [b][o][t+1] via LDS tiles
// Scans v3: c-prefetch depth 2 (consume c_t, then reload same regs with
// c_{t+2}: two MFMA phases of slack > HBM latency) + launch_bounds(256,2).
// Runtime ws_size guard: falls back to round-1 VALU path if ws too small.
// ============================================================================

constexpr int BATCH  = 16;
constexpr int CH     = 256;
constexpr int NEL    = 8192;
constexpr int NDIL   = 256;
constexpr int TSTEPS = NEL - (NDIL + 1);          // 7935
constexpr int LCH    = 16;
constexpr int NCH    = (TSTEPS + LCH - 1) / LCH;   // 496
constexpr int TPB    = 256;
constexpr int YPAD   = 260;                        // fallback scan state pad
constexpr int A2PAD  = 264;
constexpr int TTILES = (TSTEPS + 127) / 128;       // 62
constexpr int YROW   = 264;                        // bf16 state row (pad)

// workspace offsets (bytes)
constexpr size_t OFF_AF    = 0;
constexpr size_t OFF_P1    = OFF_AF    + 256 * 1024;
constexpr size_t OFF_P2    = OFF_P1    + 256 * 1024;
constexpr size_t OFF_AB16  = OFF_P2    + 256 * 1024;
constexpr size_t OFF_W1B   = OFF_AB16  + 128 * 1024;
constexpr size_t OFF_E     = OFF_W1B   + 128 * 1024;
constexpr size_t OFF_INIT  = OFF_E     + (size_t)NCH * BATCH * CH * 4;
constexpr size_t OFF_AFRAG = OFF_INIT  + (size_t)(NCH + 1) * BATCH * CH * 4;
constexpr size_t OFF_W1FR  = OFF_AFRAG + 128 * 1024;
constexpr size_t OFF_CBUF  = OFF_W1FR  + 128 * 1024;
constexpr size_t CBUF_BYTES = (size_t)(NCH * LCH) * BATCH * CH * 2;  // bf16
constexpr size_t WS_NEED   = OFF_CBUF + CBUF_BYTES;                  // ~90MB

typedef __attribute__((ext_vector_type(8))) short bf16x8;
typedef __attribute__((ext_vector_type(4))) float f32x4;

__device__ __forceinline__ float bfu(uint32_t hibits) { return __uint_as_float(hibits); }
__device__ __forceinline__ float bf2f(uint16_t b) { return __uint_as_float(((uint32_t)b) << 16); }
__device__ __forceinline__ uint16_t f2bf(float f) {          // RNE float->bf16
  uint32_t u = __float_as_uint(f);
  uint32_t r = u + 0x7fffu + ((u >> 16) & 1u);
  return (uint16_t)(r >> 16);
}

// ---------------------------------------------------------------- prep weights
// Afrag/W1frag = B-fragment-ordered (validated layout):
// frag(kb,nt): lane l, elem i  <=  M[kb*32 + (l>>4)*8 + i][nt*16 + (l&15)]
__global__ void k_prep(const float* __restrict__ w, float* __restrict__ Af,
                       uint16_t* __restrict__ Ab, uint16_t* __restrict__ W1b,
                       uint16_t* __restrict__ Afrag, uint16_t* __restrict__ W1f) {
  int o = blockIdx.x, c = threadIdx.x;
  const float2 wv = *(const float2*)&w[(size_t)(o * CH + c) * 2];
  Af[c * CH + o]  = wv.x;
  Ab[c * CH + o]  = f2bf(wv.x);
  W1b[c * CH + o] = f2bf(wv.y);
  if (Afrag) {
    int kb = c >> 5, g = (c >> 3) & 3, ii = c & 7;
    int nt = o >> 4, mm = o & 15;
    size_t idx = (((size_t)(kb * 16 + nt) * 64) + (g * 16 + mm)) * 8 + ii;
    Afrag[idx] = f2bf(wv.x);
    W1f[idx]   = f2bf(wv.y);
  }
}

__global__ void k_init0(const float* __restrict__ x, float* __restrict__ initbuf) {
  int b = blockIdx.x, c = threadIdx.x;
  initbuf[b * CH + c] = x[(size_t)(b * CH + c) * NEL];
}

__global__ __launch_bounds__(TPB) void k_sqmm(const float* __restrict__ in,
                                              float* __restrict__ outm) {
  __shared__ __align__(16) float row[CH];
  int r = blockIdx.x, o = threadIdx.x;
  row[o] = in[r * CH + o];
  __syncthreads();
  float acc = 0.f;
#pragma unroll 8
  for (int k = 0; k < CH; ++k) acc += row[k] * in[k * CH + o];
  outm[r * CH + o] = acc;
}

__global__ void k_edges(const float* __restrict__ x, float* __restrict__ out) {
  size_t base = (size_t)blockIdx.x * NEL;
  int t = threadIdx.x;
  out[base + (NEL - 256) + t] = x[base + (NEL - 256) + t];
  if (t == 0) out[base] = x[base];
}

// ------------------- MFMA cGEMM v5: cbuf[t][b*256+o] = bf16( x_{t+256} @ W1T )
// Block 512 thr (8 waves), tile 128t x 256o, one b.
// W1 frags REGISTER-resident: wave w owns n-tiles {2w,2w+1} = 16 frags
// (64 VGPRs), loaded once (128KB/block total, no per-MFMA global loads).
// x staged to LDS in A-FRAGMENT-MAJOR order: wave w stages m-tile w via 8
// coalesced dword loads per fragment -> pack -> ds_write_b128 (standard
// lane*16B pattern, conflict-free). Compute: ds_read_b128 + 2 reg-MFMAs.
__global__ __launch_bounds__(512, 4) void k_cgemm_m(const float* __restrict__ x,
                                                    const uint16_t* __restrict__ W1f,
                                                    uint16_t* __restrict__ cb) {
  __shared__ __align__(16) uint16_t Axs[64 * 64 * 8];  // [mt*8+kb][lane][8] 64KB
  int tid = threadIdx.x, bid = blockIdx.x;
  int b = bid / TTILES, tt = bid % TTILES;
  int t0 = tt * 128;
  int w = tid >> 6, l = tid & 63, lm = l & 15, g = l >> 4;
  const float* xb = x + (size_t)b * CH * NEL + (t0 + NDIL);

  // W1 fragments for this wave's 2 n-tiles (issued first; waits at first MFMA)
  bf16x8 bv[8][2];
#pragma unroll
  for (int kb = 0; kb < 8; ++kb)
#pragma unroll
    for (int p = 0; p < 2; ++p)
      bv[kb][p] =
          *(const bf16x8*)&W1f[(((size_t)(kb * 16 + w * 2 + p) * 64) + l) * 8];

  // stage x -> A-fragment-major LDS (wave w stages m-tile mt=w)
  int tA = w * 16 + lm;
#pragma unroll
  for (int kb = 0; kb < 8; ++kb) {
    float v[8];
#pragma unroll
    for (int i = 0; i < 8; ++i)
      v[i] = xb[(size_t)(kb * 32 + g * 8 + i) * NEL + tA];  // coalesced per instr
    uint4 pk;
    pk.x = (uint32_t)f2bf(v[0]) | ((uint32_t)f2bf(v[1]) << 16);
    pk.y = (uint32_t)f2bf(v[2]) | ((uint32_t)f2bf(v[3]) << 16);
    pk.z = (uint32_t)f2bf(v[4]) | ((uint32_t)f2bf(v[5]) << 16);
    pk.w = (uint32_t)f2bf(v[6]) | ((uint32_t)f2bf(v[7]) << 16);
    *(uint4*)&Axs[((w * 8 + kb) * 64 + l) * 8] = pk;  // ds_write_b128
  }
  __syncthreads();

  // compute: wave w = n-tiles {2w, 2w+1}; loop all 8 m-tiles
#pragma unroll 1
  for (int mt = 0; mt < 8; ++mt) {
    f32x4 acc0 = (f32x4)0.f, acc1 = (f32x4)0.f;
#pragma unroll
    for (int kb = 0; kb < 8; ++kb) {
      bf16x8 av = *(const bf16x8*)&Axs[((mt * 8 + kb) * 64 + l) * 8];
      acc0 = __builtin_amdgcn_mfma_f32_16x16x32_bf16(av, bv[kb][0], acc0, 0, 0, 0);
      acc1 = __builtin_amdgcn_mfma_f32_16x16x32_bf16(av, bv[kb][1], acc1, 0, 0, 0);
    }
#pragma unroll
    for (int r = 0; r < 4; ++r) {
      int t2 = t0 + mt * 16 + g * 4 + r;
      if (t2 < TSTEPS) {
        size_t base = (size_t)t2 * (BATCH * CH) + b * CH;
        cb[base + (w * 2 + 0) * 16 + lm] = f2bf(acc0[r]);
        cb[base + (w * 2 + 1) * 16 + lm] = f2bf(acc1[r]);
      }
    }
  }
}

// --------------------------------------------------- phase1 MFMA chunk scan
// v3 step: consume c_t from cc into acc FIRST, then reload the SAME cc regs
// with c_{t+2} (2 MFMA phases of slack > HBM latency). One raw barrier/step.
__device__ __forceinline__ void scan_step(
    int t, bool pref, const uint16_t* YhR, const uint16_t* YlR,
    uint16_t* YhW, uint16_t* YlW, uint16_t* __restrict__ cb,
    const bf16x8 af[8][4], ushort* cc,
    f32x4 acc[4], int w, int lm, int g) {
  bf16x8 yv[8];
#pragma unroll
  for (int kb = 0; kb < 8; ++kb)
    yv[kb] = *(const bf16x8*)&YlR[lm * YROW + kb * 32 + g * 8];
  // consume c_t into acc (before reloading cc)
#pragma unroll
  for (int ntl = 0; ntl < 4; ++ntl)
#pragma unroll
    for (int r = 0; r < 4; ++r)
      acc[ntl][r] = bfu(((uint32_t)cc[ntl * 4 + r]) << 16);
  if (pref) {  // issue c_{t+2} loads into cc (in flight for 2 steps)
    size_t cbase = (size_t)(t + 2) * (BATCH * CH);
#pragma unroll
    for (int ntl = 0; ntl < 4; ++ntl)
#pragma unroll
      for (int r = 0; r < 4; ++r)
        cc[ntl * 4 + r] = cb[cbase + (g * 4 + r) * CH + (w * 4 + ntl) * 16 + lm];
  }
  // lo pass
#pragma unroll
  for (int ntl = 0; ntl < 4; ++ntl) {
#pragma unroll
    for (int kb = 0; kb < 8; ++kb)
      acc[ntl] = __builtin_amdgcn_mfma_f32_16x16x32_bf16(yv[kb], af[kb][ntl], acc[ntl], 0, 0, 0);
  }
  // hi pass (reuse yv regs)
#pragma unroll
  for (int kb = 0; kb < 8; ++kb)
    yv[kb] = *(const bf16x8*)&YhR[lm * YROW + kb * 32 + g * 8];
#pragma unroll
  for (int ntl = 0; ntl < 4; ++ntl) {
#pragma unroll
    for (int kb = 0; kb < 8; ++kb)
      acc[ntl] = __builtin_amdgcn_mfma_f32_16x16x32_bf16(yv[kb], af[kb][ntl], acc[ntl], 0, 0, 0);
  }
  size_t ybase = (size_t)t * (BATCH * CH);
#pragma unroll
  for (int ntl = 0; ntl < 4; ++ntl)
#pragma unroll
    for (int r = 0; r < 4; ++r) {
      float v = acc[ntl][r];
      int b = g * 4 + r, o = (w * 4 + ntl) * 16 + lm;
      uint16_t hb = f2bf(v);
      cb[ybase + b * CH + o] = hb;  // ylocal in place (vmcnt; flies over barrier)
      YhW[b * YROW + o] = hb;
      YlW[b * YROW + o] = f2bf(v - bf2f(hb));
    }
  asm volatile("s_waitcnt lgkmcnt(0)" ::: "memory");
  __builtin_amdgcn_sched_barrier(0);
  __builtin_amdgcn_s_barrier();
  __builtin_amdgcn_sched_barrier(0);
}

__global__ __launch_bounds__(TPB, 2) void k_scanm(
    const uint16_t* __restrict__ Afrag, uint16_t* __restrict__ cb,
    float* __restrict__ Ebuf) {
  __shared__ __align__(16) uint16_t Yh[2][16 * YROW];
  __shared__ __align__(16) uint16_t Yl[2][16 * YROW];
  int tid = threadIdx.x;
  int j = blockIdx.x;
  int w = tid >> 6, l = tid & 63;
  int lm = l & 15, g = l >> 4;

  bf16x8 af[8][4];
#pragma unroll
  for (int kb = 0; kb < 8; ++kb)
#pragma unroll
    for (int ntl = 0; ntl < 4; ++ntl) {
      int nt = w * 4 + ntl;
      af[kb][ntl] = *(const bf16x8*)&Afrag[(((size_t)(kb * 16 + nt) * 64) + l) * 8];
    }

  for (int q = tid; q < 16 * YROW; q += TPB) { Yh[0][q] = 0; Yl[0][q] = 0; }

  int t0 = j * LCH;
  int len = min(LCH, TSTEPS - t0);
  ushort c0[16], c1[16];
  {  // prologue: load c_{t0}, c_{t0+1} in fragment order (len >= 2 always)
#pragma unroll
    for (int ntl = 0; ntl < 4; ++ntl)
#pragma unroll
      for (int r = 0; r < 4; ++r) {
        size_t off = (size_t)(g * 4 + r) * CH + (w * 4 + ntl) * 16 + lm;
        c0[ntl * 4 + r] = cb[(size_t)t0 * (BATCH * CH) + off];
        c1[ntl * 4 + r] = cb[(size_t)(t0 + 1) * (BATCH * CH) + off];
      }
  }
  __syncthreads();

  f32x4 acc[4];
#pragma unroll 1
  for (int ii = 0; ii < LCH; ii += 2) {
    if (ii >= len) break;
    scan_step(t0 + ii, ii + 2 < len, Yh[0], Yl[0], Yh[1], Yl[1], cb,
              af, c0, acc, w, lm, g);
    if (ii + 1 >= len) break;
    scan_step(t0 + ii + 1, ii + 3 < len, Yh[1], Yl[1], Yh[0], Yl[0], cb,
              af, c1, acc, w, lm, g);
  }
  // E_j = final local state (fp32, from last step's acc)
#pragma unroll
  for (int ntl = 0; ntl < 4; ++ntl) {
    int nt = w * 4 + ntl;
#pragma unroll
    for (int r = 0; r < 4; ++r) {
      int b = g * 4 + r, o = nt * 16 + lm;
      Ebuf[(size_t)j * (BATCH * CH) + b * CH + o] = acc[ntl][r];
    }
  }
}

// ------------------- binit: initbuf[k+1] = E_k + P_k @ A^L, P_k = E_{k-1}|x0
__global__ __launch_bounds__(TPB) void k_binit(const float* __restrict__ AL,
                                               const float* __restrict__ Ebuf,
                                               float* __restrict__ initbuf) {
  int k = blockIdx.x, o = threadIdx.x;
  const float* __restrict__ P =
      (k == 0) ? initbuf : (Ebuf + (size_t)(k - 1) * (BATCH * CH));
  const float* __restrict__ Ek = Ebuf + (size_t)k * (BATCH * CH);
  float acc[BATCH];
#pragma unroll
  for (int b = 0; b < BATCH; ++b) acc[b] = Ek[b * CH + o];
#pragma unroll 4
  for (int c = 0; c < CH; ++c) {
    float a = AL[c * CH + o];
#pragma unroll
    for (int b = 0; b < BATCH; ++b) acc[b] += P[b * CH + c] * a;
  }
  float* __restrict__ D = initbuf + (size_t)(k + 1) * (BATCH * CH);
#pragma unroll
  for (int b = 0; b < BATCH; ++b) D[b * CH + o] = acc[b];
}

// ------------------- corr: y_t = ylocal_t + Z_{i+1}, Z_{i+1} = Z_i @ A
// Single-bf16 correction chain. v3: convert ylocal to f32 at step start,
// then reload cc with ylocal_{t+2} (depth-2 prefetch). One barrier/step.
__device__ __forceinline__ void corr_step(
    int t, bool pref, const uint16_t* Zr, uint16_t* Zw,
    uint16_t* __restrict__ cb, const bf16x8 af[8][4],
    ushort* cc, int w, int lm, int g) {
  float yold[16];
#pragma unroll
  for (int q = 0; q < 16; ++q) yold[q] = bfu(((uint32_t)cc[q]) << 16);
  if (pref) {  // issue ylocal_{t+2} loads into cc
    size_t cbase = (size_t)(t + 2) * (BATCH * CH);
#pragma unroll
    for (int ntl = 0; ntl < 4; ++ntl)
#pragma unroll
      for (int r = 0; r < 4; ++r)
        cc[ntl * 4 + r] = cb[cbase + (g * 4 + r) * CH + (w * 4 + ntl) * 16 + lm];
  }
  bf16x8 zv[8];
#pragma unroll
  for (int kb = 0; kb < 8; ++kb)
    zv[kb] = *(const bf16x8*)&Zr[lm * YROW + kb * 32 + g * 8];
  f32x4 acc[4];
#pragma unroll
  for (int ntl = 0; ntl < 4; ++ntl) {
    acc[ntl] = (f32x4)0.f;
#pragma unroll
    for (int kb = 0; kb < 8; ++kb)
      acc[ntl] = __builtin_amdgcn_mfma_f32_16x16x32_bf16(zv[kb], af[kb][ntl], acc[ntl], 0, 0, 0);
  }
  size_t ybase = (size_t)t * (BATCH * CH);
#pragma unroll
  for (int ntl = 0; ntl < 4; ++ntl)
#pragma unroll
    for (int r = 0; r < 4; ++r) {
      int b = g * 4 + r, o = (w * 4 + ntl) * 16 + lm;
      float z = acc[ntl][r];
      float y = yold[ntl * 4 + r] + z;
      cb[ybase + b * CH + o] = f2bf(y);   // final y (global store, flies)
      Zw[b * YROW + o] = f2bf(z);
    }
  asm volatile("s_waitcnt lgkmcnt(0)" ::: "memory");
  __builtin_amdgcn_sched_barrier(0);
  __builtin_amdgcn_s_barrier();
  __builtin_amdgcn_sched_barrier(0);
}

__global__ __launch_bounds__(TPB, 2) void k_corr(
    const uint16_t* __restrict__ Afrag, uint16_t* __restrict__ cb,
    const float* __restrict__ initbuf) {
  __shared__ __align__(16) uint16_t Z[2][16 * YROW];
  int tid = threadIdx.x;
  int j = blockIdx.x;
  int w = tid >> 6, l = tid & 63;
  int lm = l & 15, g = l >> 4;

  bf16x8 af[8][4];
#pragma unroll
  for (int kb = 0; kb < 8; ++kb)
#pragma unroll
    for (int ntl = 0; ntl < 4; ++ntl) {
      int nt = w * 4 + ntl;
      af[kb][ntl] = *(const bf16x8*)&Afrag[(((size_t)(kb * 16 + nt) * 64) + l) * 8];
    }

  {  // Z_0 = bf16(B_{j-1})
    const float* I = initbuf + (size_t)j * (BATCH * CH);
    int b = tid >> 4, o0 = (tid & 15) * 16;
#pragma unroll
    for (int q = 0; q < 16; ++q)
      Z[0][b * YROW + o0 + q] = f2bf(I[b * CH + o0 + q]);
  }

  int t0 = j * LCH;
  int len = min(LCH, TSTEPS - t0);
  ushort c0[16], c1[16];
  {  // prologue: prefetch ylocal rows t0, t0+1
#pragma unroll
    for (int ntl = 0; ntl < 4; ++ntl)
#pragma unroll
      for (int r = 0; r < 4; ++r) {
        size_t off = (size_t)(g * 4 + r) * CH + (w * 4 + ntl) * 16 + lm;
        c0[ntl * 4 + r] = cb[(size_t)t0 * (BATCH * CH) + off];
        c1[ntl * 4 + r] = cb[(size_t)(t0 + 1) * (BATCH * CH) + off];
      }
  }
  __syncthreads();

#pragma unroll 1
  for (int ii = 0; ii < LCH; ii += 2) {
    if (ii >= len) break;
    corr_step(t0 + ii, ii + 2 < len, Z[0], Z[1], cb, af, c0, w, lm, g);
    if (ii + 1 >= len) break;
    corr_step(t0 + ii + 1, ii + 3 < len, Z[1], Z[0], cb, af, c1, w, lm, g);
  }
}

// ------------------- yout: transpose cbuf [t][b][o] bf16 -> out [b][o][t+1] f32
__global__ __launch_bounds__(TPB) void k_yout(const uint16_t* __restrict__ cb,
                                              float* __restrict__ out) {
  __shared__ __align__(16) float tile[64][65];
  int bid = blockIdx.x;
  int ot = bid & 3, b = (bid >> 2) & 15, tt = bid >> 6;  // tt 0..123
  int t0 = tt * 64, o0 = ot * 64;
  int tid = threadIdx.x;
  {  // load 64t x 64o bf16 (coalesced along o), convert to f32 in LDS
    int tl = tid >> 2, oq = (tid & 3) * 16;
    const uint16_t* src = &cb[(size_t)(t0 + tl) * (BATCH * CH) + b * CH + o0 + oq];
    uint4 u0 = *(const uint4*)src;
    uint4 u1 = *(const uint4*)(src + 8);
    uint32_t u[8] = {u0.x, u0.y, u0.z, u0.w, u1.x, u1.y, u1.z, u1.w};
#pragma unroll
    for (int k = 0; k < 8; ++k) {
      tile[tl][oq + 2 * k]     = bfu(u[k] << 16);
      tile[tl][oq + 2 * k + 1] = bfu(u[k] & 0xffff0000u);
    }
  }
  __syncthreads();
  {  // store 64 contiguous t per o-row (full-line writes)
    int ol = tid >> 2, tq = (tid & 3) * 16;
    float* dst = &out[(size_t)(b * CH + o0 + ol) * NEL + 1 + t0 + tq];
    if (t0 + tq + 15 < TSTEPS) {
#pragma unroll
      for (int k4 = 0; k4 < 4; ++k4) {
        float4 f;
        f.x = tile[tq + 4 * k4 + 0][ol];
        f.y = tile[tq + 4 * k4 + 1][ol];
        f.z = tile[tq + 4 * k4 + 2][ol];
        f.w = tile[tq + 4 * k4 + 3][ol];
        *(float4*)&dst[4 * k4] = f;
      }
    } else {
#pragma unroll
      for (int k = 0; k < 16; ++k)
        if (t0 + tq + k < TSTEPS) dst[k] = tile[tq + k][ol];
    }
  }
}

// ======================= fallback path (round-1, proven) =====================
__global__ __launch_bounds__(TPB) void k_cgemm_v(const float* __restrict__ x,
                                                 const uint16_t* __restrict__ W1b,
                                                 float* __restrict__ out) {
  __shared__ __align__(16) uint16_t w1[CH * 128];
  __shared__ __align__(16) float xs[32][128];
  int tid = threadIdx.x;
  int bid = blockIdx.x;
  int b = bid / (TTILES * 2);
  int rem = bid % (TTILES * 2);
  int ttile = rem >> 1, otile = rem & 1;
  int t0 = ttile * 128, o0 = otile * 128;
  int tx = tid & 15, ty = tid >> 4;
  int o8 = o0 + tx * 8;
  int tb = t0 + ty * 8;
  {
    uint4* dst = (uint4*)w1;
    for (int q = tid; q < CH * 128 / 8; q += TPB) {
      int row = q >> 4, seg = q & 15;
      dst[q] = *(const uint4*)&W1b[row * CH + o0 + seg * 8];
    }
  }
  float acc[8][8];
#pragma unroll
  for (int i = 0; i < 8; ++i)
#pragma unroll
    for (int j = 0; j < 8; ++j) acc[i][j] = 0.f;
  for (int c0 = 0; c0 < CH; c0 += 32) {
    __syncthreads();
#pragma unroll
    for (int kk = 0; kk < 4; ++kk) {
      int q = tid + kk * TPB;
      int cc = q >> 5, tf = (q & 31) * 4;
      *(float4*)&xs[cc][tf] =
          *(const float4*)&x[(size_t)(b * CH + c0 + cc) * NEL + t0 + NDIL + tf];
    }
    __syncthreads();
#pragma unroll 4
    for (int cc = 0; cc < 32; ++cc) {
      float4 xa = *(const float4*)&xs[cc][ty * 8];
      float4 xb = *(const float4*)&xs[cc][ty * 8 + 4];
      float xv[8] = {xa.x, xa.y, xa.z, xa.w, xb.x, xb.y, xb.z, xb.w};
      uint4 wv = *(const uint4*)&w1[(c0 + cc) * 128 + tx * 8];
      float wf[8] = {bfu(wv.x << 16), bfu(wv.x & 0xffff0000u),
                     bfu(wv.y << 16), bfu(wv.y & 0xffff0000u),
                     bfu(wv.z << 16), bfu(wv.z & 0xffff0000u),
                     bfu(wv.w << 16), bfu(wv.w & 0xffff0000u)};
#pragma unroll
      for (int i = 0; i < 8; ++i)
#pragma unroll
        for (int j = 0; j < 8; ++j) acc[i][j] += xv[i] * wf[j];
    }
  }
#pragma unroll
  for (int j = 0; j < 8; ++j) {
    size_t base = (size_t)(b * CH + o8 + j) * NEL + tb + 1;
#pragma unroll
    for (int i = 0; i < 8; ++i)
      if (tb + i < TSTEPS) out[base + i] = acc[i][j];
  }
}

template <bool PH3>
__global__ __launch_bounds__(TPB) void k_scan(const uint16_t* __restrict__ Ab,
                                              const float* __restrict__ initbuf,
                                              float* __restrict__ Ebuf,
                                              float* __restrict__ out) {
  __shared__ __align__(16) uint16_t Al[CH * CH];
  __shared__ __align__(16) float yl[BATCH * YPAD];
  int tid = threadIdx.x;
  int j = blockIdx.x;
  {
    const uint4* src = (const uint4*)Ab;
    uint4* dst = (uint4*)Al;
    for (int q = tid; q < CH * CH / 8; q += TPB) dst[q] = src[q];
  }
  if constexpr (PH3) {
    for (int q = tid; q < BATCH * CH / 4; q += TPB) {
      int b = q >> 6, c4 = (q & 63) * 4;
      *(float4*)&yl[b * YPAD + c4] =
          *(const float4*)&initbuf[(size_t)j * BATCH * CH + b * CH + c4];
    }
  } else {
    for (int q = tid; q < BATCH * YPAD; q += TPB) yl[q] = 0.f;
  }
  __syncthreads();
  int o4 = (tid & 63) * 4;
  int b4 = (tid >> 6) * 4;
  int len = min(LCH, TSTEPS - j * LCH);
  float acc[4][4];
  for (int i = 0; i < len; ++i) {
    int t = j * LCH + i;
    float cv[4][4];
#pragma unroll
    for (int bb = 0; bb < 4; ++bb)
#pragma unroll
      for (int oo = 0; oo < 4; ++oo)
        cv[bb][oo] = out[(size_t)((b4 + bb) * CH + o4 + oo) * NEL + t + 1];
#pragma unroll
    for (int bb = 0; bb < 4; ++bb)
#pragma unroll
      for (int oo = 0; oo < 4; ++oo) acc[bb][oo] = 0.f;
#pragma unroll 2
    for (int c = 0; c < CH; c += 4) {
      float4 v0 = *(const float4*)&yl[(b4 + 0) * YPAD + c];
      float4 v1 = *(const float4*)&yl[(b4 + 1) * YPAD + c];
      float4 v2 = *(const float4*)&yl[(b4 + 2) * YPAD + c];
      float4 v3 = *(const float4*)&yl[(b4 + 3) * YPAD + c];
      float y0[4] = {v0.x, v0.y, v0.z, v0.w};
      float y1[4] = {v1.x, v1.y, v1.z, v1.w};
      float y2[4] = {v2.x, v2.y, v2.z, v2.w};
      float y3[4] = {v3.x, v3.y, v3.z, v3.w};
#pragma unroll
      for (int k = 0; k < 4; ++k) {
        uint2 au = *(const uint2*)&Al[(c + k) * CH + o4];
        float a[4] = {bfu(au.x << 16), bfu(au.x & 0xffff0000u),
                      bfu(au.y << 16), bfu(au.y & 0xffff0000u)};
#pragma unroll
        for (int oo = 0; oo < 4; ++oo) {
          acc[0][oo] += y0[k] * a[oo];
          acc[1][oo] += y1[k] * a[oo];
          acc[2][oo] += y2[k] * a[oo];
          acc[3][oo] += y3[k] * a[oo];
        }
      }
    }
#pragma unroll
    for (int bb = 0; bb < 4; ++bb)
#pragma unroll
      for (int oo = 0; oo < 4; ++oo) acc[bb][oo] += cv[bb][oo];
    __syncthreads();
#pragma unroll
    for (int bb = 0; bb < 4; ++bb)
      *(float4*)&yl[(b4 + bb) * YPAD + o4] =
          make_float4(acc[bb][0], acc[bb][1], acc[bb][2], acc[bb][3]);
    if constexpr (PH3) {
#pragma unroll
      for (int bb = 0; bb < 4; ++bb)
#pragma unroll
        for (int oo = 0; oo < 4; ++oo)
          out[(size_t)((b4 + bb) * CH + o4 + oo) * NEL + t + 1] = acc[bb][oo];
    }
    __syncthreads();
  }
  if constexpr (!PH3) {
#pragma unroll
    for (int bb = 0; bb < 4; ++bb)
#pragma unroll
      for (int oo = 0; oo < 4; ++oo)
        Ebuf[(size_t)j * BATCH * CH + (b4 + bb) * CH + o4 + oo] = acc[bb][oo];
  }
}

__global__ __launch_bounds__(TPB) void k_phase2(const float* __restrict__ ALf,
                                                const float* __restrict__ Ebuf,
                                                float* __restrict__ initbuf) {
  __shared__ __align__(16) uint16_t At[CH * A2PAD];
  __shared__ __align__(16) float st[CH];
  int b = blockIdx.x, tid = threadIdx.x;
  for (int q = tid; q < CH * CH; q += TPB) {
    int c = q >> 8, o = q & 255;
    At[o * A2PAD + c] = f2bf(ALf[q]);
  }
  st[tid] = initbuf[b * CH + tid];
  __syncthreads();
  for (int jj = 1; jj < NCH; ++jj) {
    float acc = Ebuf[(size_t)(jj - 1) * BATCH * CH + b * CH + tid];
#pragma unroll 4
    for (int c = 0; c < CH; c += 8) {
      uint4 au = *(const uint4*)&At[tid * A2PAD + c];
      float4 s0 = *(const float4*)&st[c];
      float4 s1 = *(const float4*)&st[c + 4];
      acc += bfu(au.x << 16) * s0.x + bfu(au.x & 0xffff0000u) * s0.y +
             bfu(au.y << 16) * s0.z + bfu(au.y & 0xffff0000u) * s0.w +
             bfu(au.z << 16) * s1.x + bfu(au.z & 0xffff0000u) * s1.y +
             bfu(au.w << 16) * s1.z + bfu(au.w & 0xffff0000u) * s1.w;
    }
    __syncthreads();
    st[tid] = acc;
    initbuf[(size_t)jj * BATCH * CH + b * CH + tid] = acc;
    __syncthreads();
  }
}

// ============================================================================
extern "C" void kernel_launch(void* const* d_in, const int* in_sizes, int n_in,
                              void* d_out, int out_size, void* d_ws, size_t ws_size,
                              hipStream_t stream) {
  const float* x = (const float*)d_in[0];
  const float* w = (const float*)d_in[1];
  float* out = (float*)d_out;
  char* ws = (char*)d_ws;

  float*    Af    = (float*)(ws + OFF_AF);
  float*    P1    = (float*)(ws + OFF_P1);
  float*    P2    = (float*)(ws + OFF_P2);
  uint16_t* Ab    = (uint16_t*)(ws + OFF_AB16);
  uint16_t* W1b   = (uint16_t*)(ws + OFF_W1B);
  float*    Ebuf  = (float*)(ws + OFF_E);
  float*    inb   = (float*)(ws + OFF_INIT);
  uint16_t* Afrag = (uint16_t*)(ws + OFF_AFRAG);
  uint16_t* W1f   = (uint16_t*)(ws + OFF_W1FR);
  uint16_t* cbuf  = (uint16_t*)(ws + OFF_CBUF);

  const bool fast = ws_size >= WS_NEED;

  k_prep<<<CH, CH, 0, stream>>>(w, Af, Ab, W1b, fast ? Afrag : nullptr, W1f);
  k_init0<<<BATCH, CH, 0, stream>>>(x, inb);
  k_sqmm<<<CH, TPB, 0, stream>>>(Af, P1);   // A^2
  k_sqmm<<<CH, TPB, 0, stream>>>(P1, P2);   // A^4
  k_sqmm<<<CH, TPB, 0, stream>>>(P2, P1);   // A^8
  k_sqmm<<<CH, TPB, 0, stream>>>(P1, P2);   // A^16 (= A^LCH)
  k_edges<<<BATCH * CH, 256, 0, stream>>>(x, out);
  if (fast) {
    k_cgemm_m<<<BATCH * TTILES, 512, 0, stream>>>(x, W1f, cbuf);
    k_scanm<<<NCH, TPB, 0, stream>>>(Afrag, cbuf, Ebuf);
    k_binit<<<NCH - 1, TPB, 0, stream>>>(P2, Ebuf, inb);
    k_corr<<<NCH, TPB, 0, stream>>>(Afrag, cbuf, inb);
    k_yout<<<124 * 64, TPB, 0, stream>>>(cbuf, out);
  } else {
    k_cgemm_v<<<BATCH * TTILES * 2, TPB, 0, stream>>>(x, W1b, out);
    k_scan<false><<<NCH - 1, TPB, 0, stream>>>(Ab, nullptr, Ebuf, out);
    k_phase2<<<BATCH, TPB, 0, stream>>>(P2, Ebuf, inb);
    k_scan<true><<<NCH, TPB, 0, stream>>>(Ab, inb, nullptr, out);
  }
}